// Round 1
// baseline (1519.164 us; speedup 1.0000x reference)
//
#include <hip/hip_runtime.h>
#include <math.h>

constexpr int RVQ_N = 262144;
constexpr int RVQ_D = 64;
constexpr int RVQ_L = 4;
constexpr int RVQ_K = 1024;

typedef __attribute__((ext_vector_type(8))) short short8;
typedef __attribute__((ext_vector_type(4))) float floatx4;

// ---- bf16 split helpers (RNE) ----
__device__ __forceinline__ unsigned short f2bf(float f) {
  unsigned int u = __float_as_uint(f);
  u += 0x7fffu + ((u >> 16) & 1u);
  return (unsigned short)(u >> 16);
}
__device__ __forceinline__ float bf2f(unsigned short h) {
  return __uint_as_float(((unsigned int)h) << 16);
}
__device__ __forceinline__ void split2(float x, unsigned short& h0,
                                       unsigned short& h1) {
  h0 = f2bf(x);
  float r1 = x - bf2f(h0);
  h1 = f2bf(r1);
}
__device__ __forceinline__ void load8(const float* p, float* v) {
  float4 a = *(const float4*)p;
  float4 b = *(const float4*)(p + 4);
  v[0] = a.x; v[1] = a.y; v[2] = a.z; v[3] = a.w;
  v[4] = b.x; v[5] = b.y; v[6] = b.z; v[7] = b.w;
}

// top-2 insert helper: median of {p1,p2,u} is the new second-best (p1<=p2).
__device__ __forceinline__ unsigned med3u(unsigned a, unsigned b, unsigned c) {
  unsigned d;
  asm("v_med3_u32 %0, %1, %2, %3" : "=v"(d) : "v"(a), "v"(b), "v"(c));
  return d;
}

// ---------------------------------------------------------------------------
// Prep 1: split -2*codebook into hi/mid bf16 arrays [L*K*D each]
// ---------------------------------------------------------------------------
__global__ __launch_bounds__(256) void rvq_prep_split(
    const float* __restrict__ cb, unsigned short* __restrict__ bh,
    unsigned short* __restrict__ bm) {
  int i = blockIdx.x * 256 + threadIdx.x;
  float c2 = -2.0f * cb[i];
  unsigned short h0, h1;
  split2(c2, h0, h1);
  bh[i] = h0;
  bm[i] = h1;
}

// ---------------------------------------------------------------------------
// Prep 2: per-center squared norms. Raw (R1-verbatim, for rescue) + biased
// (+256 so MFMA scores = ||r-c||^2 + 256 > 0 -> uint-compare monotone).
// ---------------------------------------------------------------------------
__global__ __launch_bounds__(256) void rvq_cnorm_kernel(
    const float* __restrict__ cb, float* __restrict__ cnorm,
    float* __restrict__ cnormB) {
  int i = blockIdx.x * blockDim.x + threadIdx.x;
  const float* c = cb + (size_t)i * RVQ_D;
  float a0 = 0.f, a1 = 0.f, a2 = 0.f, a3 = 0.f;
#pragma unroll
  for (int d = 0; d < RVQ_D; d += 4) {
    float4 v = *reinterpret_cast<const float4*>(c + d);
    a0 = fmaf(v.x, v.x, a0);
    a1 = fmaf(v.y, v.y, a1);
    a2 = fmaf(v.z, v.z, a2);
    a3 = fmaf(v.w, v.w, a3);
  }
  float s = (a0 + a1) + (a2 + a3);
  cnorm[i] = s;
  cnormB[i] = s + 256.0f;
}

// B-tile fragment loader: hi/mid x 2 dim-octets + biased cnorm
__device__ __forceinline__ void load_bt(const unsigned short* __restrict__ bh,
                                        const unsigned short* __restrict__ bmp,
                                        const float* __restrict__ cnl, int nt,
                                        int m, int q, short8 (&b)[2][2],
                                        float& cc) {
  size_t rowoff = (size_t)(nt * 16 + m) * RVQ_D + q * 8;
  b[0][0] = *(const short8*)(bh + rowoff);
  b[0][1] = *(const short8*)(bh + rowoff + 32);
  b[1][0] = *(const short8*)(bmp + rowoff);
  b[1][1] = *(const short8*)(bmp + rowoff + 32);
  cc = cnl[nt * 16 + m];
}

// ---------------------------------------------------------------------------
// Main fused kernel. No LDS, no barriers. Each wave owns 64 points; each
// level's K-scan is done in TWO passes over the B stream, each pass covering
// half of the wave's A tiles (t in {0,1} then {2,3}). This halves the live
// fragment state (afr 64->32 regs, p1/p2 32->16, acc 16->8) so the combined
// VGPR+AGPR footprint fits 4 waves/SIMD (<=128 regs, enforced by
// __launch_bounds__(256,4)) instead of 2 -- the B stream (L2-resident, 512KB
// per level) is simply read twice per wave, which is cheap.
// Packed-uint top-2 scan nominates; R1-verbatim fp32 rescue decides.
// ---------------------------------------------------------------------------
__global__ __launch_bounds__(256, 4) void rvq_mfma_kernel(
    const float* __restrict__ feat, const float* __restrict__ cb,
    const unsigned short* __restrict__ cb_hi,
    const unsigned short* __restrict__ cb_mid,
    const float* __restrict__ cnorm, const float* __restrict__ cnormB,
    float* __restrict__ out_q, float* __restrict__ out_idx) {
  const int tid = threadIdx.x;
  const int lane = tid & 63;
  const int wave = tid >> 6;
  const int m = lane & 15;  // column (B center / C col / A row)
  const int q = lane >> 4;  // quad (k-octet / C row-group)
  const int base = blockIdx.x * 256 + wave * 64;  // wave's first point
  const int g = base + lane;                      // this lane's own point

  int ci0 = 0, ci1 = 0, ci2 = 0;  // chosen-index chain (own point)

  // products kept: hi*hi, hi*mid, mid*hi
  constexpr int AC[3] = {0, 0, 1};
  constexpr int BC[3] = {0, 1, 0};

#pragma unroll
  for (int l = 0; l < RVQ_L; ++l) {
    const unsigned short* bh = cb_hi + (size_t)l * RVQ_K * RVQ_D;
    const unsigned short* bmp = cb_mid + (size_t)l * RVQ_K * RVQ_D;
    const float* cnBl = cnormB + (size_t)l * RVQ_K;
    const float* cnl = cnorm + (size_t)l * RVQ_K;
    const float* cbl = cb + (size_t)l * RVQ_K * RVQ_D;

    int cand[4] = {0, 0, 0, 0};

#pragma unroll
    for (int pass = 0; pass < 2; ++pass) {
      // ---- A-fragment regen for this pass's two 16-point tiles ----
      short8 afr[2][2][2];
#pragma unroll
      for (int tl = 0; tl < 2; ++tl) {
        const int t = pass * 2 + tl;
        const int p = t * 16 + m;
        int j0 = 0, j1 = 0, j2 = 0;
        if (l > 0) j0 = __shfl(ci0, p);
        if (l > 1) j1 = __shfl(ci1, p);
        if (l > 2) j2 = __shfl(ci2, p);
        const float* fp = feat + (size_t)(base + p) * RVQ_D;
        const float* c0p = cb + (size_t)j0 * RVQ_D;
        const float* c1p = cb + ((size_t)RVQ_K + j1) * RVQ_D;
        const float* c2p = cb + ((size_t)2 * RVQ_K + j2) * RVQ_D;
#pragma unroll
        for (int oct = 0; oct < 2; ++oct) {
          const int dof = oct * 32 + q * 8;
          float v[8];
          load8(fp + dof, v);
          if (l > 0) {
            float c[8];
            load8(c0p + dof, c);
#pragma unroll
            for (int e = 0; e < 8; ++e) v[e] -= c[e];
          }
          if (l > 1) {
            float c[8];
            load8(c1p + dof, c);
#pragma unroll
            for (int e = 0; e < 8; ++e) v[e] -= c[e];
          }
          if (l > 2) {
            float c[8];
            load8(c2p + dof, c);
#pragma unroll
            for (int e = 0; e < 8; ++e) v[e] -= c[e];
          }
#pragma unroll
          for (int e = 0; e < 8; ++e) {
            unsigned short h0, h1;
            split2(v[e], h0, h1);
            afr[tl][0][oct][e] = (short)h0;
            afr[tl][1][oct][e] = (short)h1;
          }
        }
      }

      // ---- packed top-2 MFMA scan, double-buffered B ----
      unsigned p1[2][4], p2[2][4];
#pragma unroll
      for (int tl = 0; tl < 2; ++tl)
#pragma unroll
        for (int r2 = 0; r2 < 4; ++r2) {
          p1[tl][r2] = 0xFFFFFFFFu;
          p2[tl][r2] = 0xFFFFFFFFu;
        }

      short8 bA[2][2], bB[2][2];
      float ccA, ccB;
      load_bt(bh, bmp, cnBl, 0, m, q, bA, ccA);

      for (int nt = 0; nt < RVQ_K / 16; nt += 2) {
        load_bt(bh, bmp, cnBl, nt + 1, m, q, bB, ccB);
        {  // even tile
          floatx4 acc[2];
#pragma unroll
          for (int tl = 0; tl < 2; ++tl) {
            acc[tl][0] = ccA; acc[tl][1] = ccA;
            acc[tl][2] = ccA; acc[tl][3] = ccA;
          }
#pragma unroll
          for (int s = 0; s < 3; ++s)
#pragma unroll
            for (int oct = 0; oct < 2; ++oct)
#pragma unroll
              for (int tl = 0; tl < 2; ++tl)
                acc[tl] = __builtin_amdgcn_mfma_f32_16x16x32_bf16(
                    afr[tl][AC[s]][oct], bA[BC[s]][oct], acc[tl], 0, 0, 0);
          unsigned nbits = (unsigned)nt;
#pragma unroll
          for (int tl = 0; tl < 2; ++tl)
#pragma unroll
            for (int r2 = 0; r2 < 4; ++r2) {
              unsigned u =
                  (__float_as_uint(acc[tl][r2]) & 0xFFFFFFC0u) | nbits;
              p2[tl][r2] = med3u(p1[tl][r2], p2[tl][r2], u);
              p1[tl][r2] = p1[tl][r2] < u ? p1[tl][r2] : u;
            }
        }
        int ntn = (nt + 2 < RVQ_K / 16) ? nt + 2 : nt;
        load_bt(bh, bmp, cnBl, ntn, m, q, bA, ccA);
        {  // odd tile
          floatx4 acc[2];
#pragma unroll
          for (int tl = 0; tl < 2; ++tl) {
            acc[tl][0] = ccB; acc[tl][1] = ccB;
            acc[tl][2] = ccB; acc[tl][3] = ccB;
          }
#pragma unroll
          for (int s = 0; s < 3; ++s)
#pragma unroll
            for (int oct = 0; oct < 2; ++oct)
#pragma unroll
              for (int tl = 0; tl < 2; ++tl)
                acc[tl] = __builtin_amdgcn_mfma_f32_16x16x32_bf16(
                    afr[tl][AC[s]][oct], bB[BC[s]][oct], acc[tl], 0, 0, 0);
          unsigned nbits = (unsigned)(nt + 1);
#pragma unroll
          for (int tl = 0; tl < 2; ++tl)
#pragma unroll
            for (int r2 = 0; r2 < 4; ++r2) {
              unsigned u =
                  (__float_as_uint(acc[tl][r2]) & 0xFFFFFFC0u) | nbits;
              p2[tl][r2] = med3u(p1[tl][r2], p2[tl][r2], u);
              p1[tl][r2] = p1[tl][r2] < u ? p1[tl][r2] : u;
            }
        }
      }

      // ---- top-4 per point via 4 masked butterfly-min passes ----
      const int srcl = ((lane >> 2) & 3) << 4;
#pragma unroll
      for (int tl = 0; tl < 2; ++tl) {
        const int t = pass * 2 + tl;
#pragma unroll
        for (int r2 = 0; r2 < 4; ++r2) {
          unsigned a = p1[tl][r2], b = p2[tl][r2];
          int ka = (int)((a & 63u) << 4) | m;
          int kb = (int)((b & 63u) << 4) | m;
          unsigned va = (a & 0xFFFFFC00u) | (unsigned)ka;  // 10-bit k embedded
          unsigned vb = (b & 0xFFFFFC00u) | (unsigned)kb;
          if (vb < va) { unsigned tu = va; va = vb; vb = tu; }
          int ck[4];
#pragma unroll
          for (int pss = 0; pss < 4; ++pss) {
            unsigned gm = va;
#pragma unroll
            for (int off = 1; off <= 8; off <<= 1) {
              unsigned o = (unsigned)__shfl_xor((int)gm, off);
              gm = gm < o ? gm : o;
            }
            ck[pss] = (int)(gm & 1023u);
            bool hit = (va == gm);
            va = hit ? vb : va;
            vb = hit ? 0xFFFFFFFFu : vb;
          }
          int v1 = __shfl(ck[0], srcl);
          int v2 = __shfl(ck[1], srcl);
          int v3 = __shfl(ck[2], srcl);
          int v4 = __shfl(ck[3], srcl);
          bool take = (q == t) && ((lane & 3) == r2);
          if (take) { cand[0] = v1; cand[1] = v2; cand[2] = v3; cand[3] = v4; }
        }
      }
    }  // pass

    // ---- exact fp32 rescue (R1-verbatim scoring) on own point ----
    {
      int tmp;
      if (cand[0] > cand[1]) { tmp = cand[0]; cand[0] = cand[1]; cand[1] = tmp; }
      if (cand[2] > cand[3]) { tmp = cand[2]; cand[2] = cand[3]; cand[3] = tmp; }
      if (cand[0] > cand[2]) { tmp = cand[0]; cand[0] = cand[2]; cand[2] = tmp; }
      if (cand[1] > cand[3]) { tmp = cand[1]; cand[1] = cand[3]; cand[3] = tmp; }
      if (cand[1] > cand[2]) { tmp = cand[1]; cand[1] = cand[2]; cand[2] = tmp; }
    }

    float r_[RVQ_D];
    {
      const float4* f4p = (const float4*)(feat + (size_t)g * RVQ_D);
#pragma unroll
      for (int i = 0; i < 16; ++i) {
        float4 v = f4p[i];
        r_[4 * i + 0] = v.x; r_[4 * i + 1] = v.y;
        r_[4 * i + 2] = v.z; r_[4 * i + 3] = v.w;
      }
      if (l > 0) {
        const float4* cp = (const float4*)(cb + (size_t)ci0 * RVQ_D);
#pragma unroll
        for (int i = 0; i < 16; ++i) {
          float4 v = cp[i];
          r_[4 * i + 0] -= v.x; r_[4 * i + 1] -= v.y;
          r_[4 * i + 2] -= v.z; r_[4 * i + 3] -= v.w;
        }
      }
      if (l > 1) {
        const float4* cp = (const float4*)(cb + ((size_t)RVQ_K + ci1) * RVQ_D);
#pragma unroll
        for (int i = 0; i < 16; ++i) {
          float4 v = cp[i];
          r_[4 * i + 0] -= v.x; r_[4 * i + 1] -= v.y;
          r_[4 * i + 2] -= v.z; r_[4 * i + 3] -= v.w;
        }
      }
      if (l > 2) {
        const float4* cp =
            (const float4*)(cb + ((size_t)2 * RVQ_K + ci2) * RVQ_D);
#pragma unroll
        for (int i = 0; i < 16; ++i) {
          float4 v = cp[i];
          r_[4 * i + 0] -= v.x; r_[4 * i + 1] -= v.y;
          r_[4 * i + 2] -= v.z; r_[4 * i + 3] -= v.w;
        }
      }
    }

    float s0 = 0.f, s1 = 0.f, s2 = 0.f, s3 = 0.f;
#pragma unroll
    for (int i = 0; i < 16; ++i) {
      s0 = fmaf(r_[4 * i + 0], r_[4 * i + 0], s0);
      s1 = fmaf(r_[4 * i + 1], r_[4 * i + 1], s1);
      s2 = fmaf(r_[4 * i + 2], r_[4 * i + 2], s2);
      s3 = fmaf(r_[4 * i + 3], r_[4 * i + 3], s3);
    }
    const float rr = (s0 + s1) + (s2 + s3);

    float best = INFINITY;
    int ci = 0;
#pragma unroll
    for (int jc = 0; jc < 4; ++jc) {
      int k = cand[jc];
      const float4* c4 = (const float4*)(cbl + (size_t)k * RVQ_D);
      float a0 = 0.f, a1 = 0.f, a2 = 0.f, a3 = 0.f;
#pragma unroll
      for (int i = 0; i < 16; ++i) {
        float4 v = c4[i];
        a0 = fmaf(r_[4 * i + 0], v.x, a0);
        a1 = fmaf(r_[4 * i + 1], v.y, a1);
        a2 = fmaf(r_[4 * i + 2], v.z, a2);
        a3 = fmaf(r_[4 * i + 3], v.w, a3);
      }
      float dot = (a0 + a1) + (a2 + a3);
      float score = (rr - 2.0f * dot) + cnl[k];
      if (score < best) {
        best = score;
        ci = k;
      }
    }

    if (l == 0) ci0 = ci;
    else if (l == 1) ci1 = ci;
    else if (l == 2) ci2 = ci;

    if (l == RVQ_L - 1) {
      // out = features - final residual (rn = r - c_ci), exact fp32
      const float4* crow = (const float4*)(cbl + (size_t)ci * RVQ_D);
      const float4* f4p = (const float4*)(feat + (size_t)g * RVQ_D);
      float4* o4 = (float4*)(out_q + (size_t)g * RVQ_D);
#pragma unroll
      for (int i = 0; i < 16; ++i) {
        float4 cv = crow[i];
        float4 fv = f4p[i];
        float rn0 = r_[4 * i + 0] - cv.x;
        float rn1 = r_[4 * i + 1] - cv.y;
        float rn2 = r_[4 * i + 2] - cv.z;
        float rn3 = r_[4 * i + 3] - cv.w;
        float4 o;
        o.x = fv.x - rn0;
        o.y = fv.y - rn1;
        o.z = fv.z - rn2;
        o.w = fv.w - rn3;
        o4[i] = o;
      }
    }
    out_idx[(size_t)l * RVQ_N + g] = (float)ci;
  }
}

extern "C" void kernel_launch(void* const* d_in, const int* in_sizes, int n_in,
                              void* d_out, int out_size, void* d_ws,
                              size_t ws_size, hipStream_t stream) {
  const float* features = (const float*)d_in[0];   // [N, D]
  const float* codebooks = (const float*)d_in[1];  // [L, K, D]
  float* out_q = (float*)d_out;                    // [N, D]
  float* out_idx = (float*)d_out + (size_t)RVQ_N * RVQ_D;  // [L, N]

  const size_t comp_elems = (size_t)RVQ_L * RVQ_K * RVQ_D;  // 262144
  unsigned short* cb_hi = (unsigned short*)d_ws;
  unsigned short* cb_mid = cb_hi + comp_elems;
  float* cnorm = (float*)(cb_mid + comp_elems);   // [L*K] raw
  float* cnormB = cnorm + (size_t)RVQ_L * RVQ_K;  // [L*K] +256 biased

  hipLaunchKernelGGL(rvq_prep_split, dim3(comp_elems / 256), dim3(256), 0,
                     stream, codebooks, cb_hi, cb_mid);
  hipLaunchKernelGGL(rvq_cnorm_kernel, dim3((RVQ_L * RVQ_K) / 256), dim3(256),
                     0, stream, codebooks, cnorm, cnormB);
  hipLaunchKernelGGL(rvq_mfma_kernel, dim3(RVQ_N / 256), dim3(256), 0, stream,
                     features, codebooks, cb_hi, cb_mid, cnorm, cnormB, out_q,
                     out_idx);
}